// Round 10
// baseline (249.835 us; speedup 1.0000x reference)
//
#include <hip/hip_runtime.h>

#define DEV __device__ __forceinline__

struct F3 { float x, y, z; };
DEV F3 mk3(float a, float b, float c) { F3 r; r.x = a; r.y = b; r.z = c; return r; }
DEV F3 sub3(F3 a, F3 b) { return mk3(a.x - b.x, a.y - b.y, a.z - b.z); }
DEV F3 cross3(F3 a, F3 b) {
    return mk3(a.y*b.z - a.z*b.y, a.z*b.x - a.x*b.z, a.x*b.y - a.y*b.x);
}
DEV float cosv(F3 a, F3 b) {
    float num = a.x*b.x + a.y*b.y + a.z*b.z;
    float na  = a.x*a.x + a.y*a.y + a.z*a.z;
    float nb  = b.x*b.x + b.y*b.y + b.z*b.z;
    return num * rsqrtf(na * nb);
}

constexpr int ROWS = 32;    // rows per tile (small tile -> regs for DEPTH-2 prefetch)
constexpr int TPB  = 64;    // one wave per block: barrier-free wave-synchronous LDS
constexpr int PSTR = 73;    // padded pred row stride (odd -> conflict-free compute reads)
constexpr int TSTR = 79;    // padded targ row stride (odd)
constexpr int LDS_BYTES = ROWS * (PSTR + TSTR) * 4;  // 19,456 B -> 8 blocks/CU
constexpr int NBMAX = 2048; // 8 blocks/CU * 256 CUs, all resident

constexpr int NP4  = ROWS * 18 / 64;      // 9 pred float4 granules per lane
constexpr int TG4  = ROWS * 78 / 4;       // 624 targ float4 granules per tile
constexpr int NT4F = 9;                   // full targ steps; remainder 48 granules (lanes<48)

__global__ __launch_bounds__(TPB, 2) void ori_loss_main(
    const float* __restrict__ scale,
    const int*   __restrict__ sidx,
    const int*   __restrict__ didx,
    const float* __restrict__ pred,
    const float* __restrict__ targ,
    int B, int ntiles, int nb,
    float* __restrict__ partial)
{
    extern __shared__ float lds[];
    float* lp = lds;               // [ROWS][PSTR]
    float* lt = lds + ROWS * PSTR; // [ROWS][TSTR]

    const int tid = threadIdx.x;
    const float s = scale[0];

    // wave-uniform gather indices -> SGPRs
    int sj[14], dj[14];
    #pragma unroll
    for (int k = 0; k < 14; ++k) { sj[k] = sidx[k] * 3; dj[k] = didx[k] * 3; }

    const float4* gp  = (const float4*)pred;  // B*18 granules
    const float4* gt4 = (const float4*)targ;  // B*78/4 granules
    const long maxp  = (long)B * 18 - 1;
    const long maxt4 = (long)B * 78 / 4 - 1;

    // DEPTH-2: two statically-named register buffers (no runtime indexing)
    float4 bpA[NP4], btA[NT4F + 1];
    float4 bpB[NP4], btB[NT4F + 1];

#define LOAD_PRED(buf, t)                                                      \
    { long basep = (long)(t) * (ROWS * 18);                                    \
      _Pragma("unroll")                                                        \
      for (int k = 0; k < NP4; ++k) {                                          \
          long i = basep + tid + TPB * k;                                      \
          buf[k] = gp[i > maxp ? maxp : i];                                    \
      } }
#define LOAD_TARG(buf, t)                                                      \
    { long baset = (long)(t) * TG4;                                            \
      _Pragma("unroll")                                                        \
      for (int k = 0; k < NT4F; ++k) {                                         \
          long i = baset + tid + TPB * k;                                      \
          buf[k] = gt4[i > maxt4 ? maxt4 : i];                                 \
      }                                                                        \
      { long i = baset + NT4F * TPB + tid;  /* rem granules; lanes>=48 dup */  \
        buf[NT4F] = gt4[i > maxt4 ? maxt4 : i]; } }

    // scatter one targ granule into padded LDS rows
    auto put_targ = [&](int gg, float4 v) {
        int f = gg * 4;
        int r = f / 78;
        int j = f - r * 78;       // even, 0..76
        float* d = lt + r * TSTR + j;
        if (j < 76) {
            d[0] = v.x; d[1] = v.y; d[2] = v.z; d[3] = v.w;
        } else {                  // straddles rows r / r+1
            d[0] = v.x; d[1] = v.y;
            float* d2 = lt + (r + 1) * TSTR;
            d2[0] = v.z; d2[1] = v.w;
        }
    };
    auto put_pred = [&](int gg, float4 v) {
        int r = gg / 18, j = gg - r * 18;
        float* d = lp + r * PSTR + j * 4;
        d[0] = v.x; d[1] = v.y; d[2] = v.z; d[3] = v.w;
    };

#define WRITE_TILE(bt, bp)                                                     \
    { _Pragma("unroll")                                                        \
      for (int k = 0; k < NT4F; ++k) put_targ(tid + TPB * k, bt[k]);           \
      if (tid < TG4 - NT4F * TPB) put_targ(tid + TPB * NT4F, bt[NT4F]);        \
      _Pragma("unroll")                                                        \
      for (int k = 0; k < NP4; ++k) put_pred(tid + TPB * k, bp[k]); }

    float sumj = 0.0f, sumc = 0.0f;

    auto compute = [&](int t) {
        int rows = min(ROWS, B - t * ROWS);
        if (tid < rows) {
            const float* pr = lp + tid * PSTR;
            const float* tr = lt + tid * TSTR;

            #pragma unroll
            for (int k = 0; k < 14; ++k) {
                #pragma unroll
                for (int c = 0; c < 3; ++c) {
                    float d  = s * pr[sj[k] + c] - tr[dj[k] + c];
                    float ad = fabsf(d);
                    sumj += (ad < 1.0f) ? 0.5f * d * d : (ad - 0.5f);
                }
            }

            #define P3(j) mk3(pr[(j)*3], pr[(j)*3+1], pr[(j)*3+2])
            #define T3(j) mk3(tr[(j)*3], tr[(j)*3+1], tr[(j)*3+2])
            sumc += cosv(cross3(sub3(P3(2), P3(0)), sub3(P3(1), P3(0))),
                         cross3(sub3(T3(22), T3(1)), sub3(T3(18), T3(1))));
            sumc += cosv(cross3(sub3(P3(13), P3(9)), sub3(P3(14), P3(9))),
                         cross3(sub3(T3(3), T3(2)), sub3(T3(11), T3(2))));
            #define DIR(pa, pb, ta, tb) sumc += cosv(sub3(P3(pa), P3(pb)), sub3(T3(ta), T3(tb)));
            DIR(2, 1, 22, 18)
            DIR(14, 13, 11, 4)
            DIR(6, 3, 2, 1)
            DIR(5, 2, 23, 22)
            DIR(4, 1, 19, 18)
            DIR(8, 5, 24, 23)
            DIR(7, 4, 20, 19)
            DIR(11, 8, 25, 24)
            DIR(10, 7, 21, 20)
            DIR(19, 17, 13, 12)
            DIR(18, 16, 6, 5)
            DIR(21, 19, 14, 13)
            DIR(20, 18, 7, 6)
            #undef DIR
            #undef P3
            #undef T3
        }
    };

    int t = blockIdx.x;
    // prologue: tiles t -> A, t+nb -> B, both in flight
    LOAD_TARG(btA, t)
    LOAD_PRED(bpA, t)
    {
        int t1 = t + nb;
        if (t1 < ntiles) { LOAD_TARG(btB, t1) LOAD_PRED(bpB, t1) }
    }

    for (;;) {
        int t1 = t + nb, t2 = t + 2 * nb;

        // ---- stage A (tile t), re-arm A with tile t+2nb ----
        WRITE_TILE(btA, bpA)
        if (t2 < ntiles) { LOAD_TARG(btA, t2) LOAD_PRED(bpA, t2) }
        asm volatile("" ::: "memory");
        compute(t);
        if (t1 >= ntiles) break;

        // ---- stage B (tile t+nb), re-arm B with tile t+3nb ----
        {
            int t3 = t + 3 * nb;
            WRITE_TILE(btB, bpB)
            if (t3 < ntiles) { LOAD_TARG(btB, t3) LOAD_PRED(bpB, t3) }
        }
        asm volatile("" ::: "memory");
        compute(t1);
        if (t2 >= ntiles) break;
        t = t2;
    }

    // ---- single-wave reduction (upper lanes hold 0) ----
    #pragma unroll
    for (int off = 32; off; off >>= 1) {
        sumj += __shfl_down(sumj, off);
        sumc += __shfl_down(sumc, off);
    }
    if (tid == 0) {
        partial[blockIdx.x]      = sumj;
        partial[nb + blockIdx.x] = sumc;
    }
#undef LOAD_PRED
#undef LOAD_TARG
#undef WRITE_TILE
}

__global__ __launch_bounds__(256) void ori_loss_final(
    const float* __restrict__ partial, int nblk, int B, float* __restrict__ out)
{
    double dj = 0.0, dc = 0.0;
    for (int i = threadIdx.x; i < nblk; i += 256) {
        dj += (double)partial[i];
        dc += (double)partial[nblk + i];
    }
    #pragma unroll
    for (int off = 32; off; off >>= 1) {
        dj += __shfl_down(dj, off);
        dc += __shfl_down(dc, off);
    }
    __shared__ double wj[4], wc[4];
    int wid  = threadIdx.x >> 6;
    int lane = threadIdx.x & 63;
    if (lane == 0) { wj[wid] = dj; wc[wid] = dc; }
    __syncthreads();
    if (threadIdx.x == 0) {
        double J = wj[0] + wj[1] + wj[2] + wj[3];
        double C = wc[0] + wc[1] + wc[2] + wc[3];
        double jtr  = J / ((double)B * 42.0);
        double loss = jtr + 15.0 - C / (double)B;
        out[0] = (float)loss;
        out[1] = (float)jtr;
    }
}

extern "C" void kernel_launch(void* const* d_in, const int* in_sizes, int n_in,
                              void* d_out, int out_size, void* d_ws, size_t ws_size,
                              hipStream_t stream) {
    const float* scale = (const float*)d_in[0];
    const int*   sidx  = (const int*)d_in[1];
    const int*   didx  = (const int*)d_in[2];
    const float* pred  = (const float*)d_in[3];
    const float* targ  = (const float*)d_in[4];

    int B      = in_sizes[3] / 72;               // pred_jtr is [B, 24, 3]
    int ntiles = (B + ROWS - 1) / ROWS;
    int nb     = ntiles < NBMAX ? ntiles : NBMAX;

    float* partial = (float*)d_ws;
    float* out     = (float*)d_out;

    ori_loss_main<<<nb, TPB, LDS_BYTES, stream>>>(scale, sidx, didx, pred, targ,
                                                  B, ntiles, nb, partial);
    ori_loss_final<<<1, 256, 0, stream>>>(partial, nb, B, out);
}

// Round 11
// 138.012 us; speedup vs baseline: 1.8102x; 1.8102x over previous
//
#include <hip/hip_runtime.h>

#define DEV __device__ __forceinline__

struct F3 { float x, y, z; };
DEV F3 mk3(float a, float b, float c) { F3 r; r.x = a; r.y = b; r.z = c; return r; }
DEV F3 sub3(F3 a, F3 b) { return mk3(a.x - b.x, a.y - b.y, a.z - b.z); }
DEV F3 cross3(F3 a, F3 b) {
    return mk3(a.y*b.z - a.z*b.y, a.z*b.x - a.x*b.z, a.x*b.y - a.y*b.x);
}
DEV float cosv(F3 a, F3 b) {
    float num = a.x*b.x + a.y*b.y + a.z*b.z;
    float na  = a.x*a.x + a.y*a.y + a.z*a.z;
    float nb  = b.x*b.x + b.y*b.y + b.z*b.z;
    return num * rsqrtf(na * nb);
}

constexpr int ROWS = 32;    // rows per tile (small tile -> regs for DEPTH-2 prefetch)
constexpr int TPB  = 64;    // one wave per block: barrier-free wave-synchronous LDS
constexpr int PSTR = 73;    // padded pred row stride (odd -> conflict-free compute reads)
constexpr int TSTR = 79;    // padded targ row stride (odd)
constexpr int LDS_BYTES = ROWS * (PSTR + TSTR) * 4;  // 19,456 B -> 8 blocks/CU
constexpr int NBMAX = 2048; // 8 blocks/CU * 256 CUs, all resident

constexpr int NP4  = ROWS * 18 / 64;      // 9 pred float4 granules per lane
constexpr int TG4  = ROWS * 78 / 4;       // 624 targ float4 granules per tile
constexpr int NT4F = 9;                   // full targ steps; remainder 48 granules (lanes<48)

// NOTE: no min-waves arg — R10's __launch_bounds__(64,2) made the allocator
// cap at 128 VGPR and spill the staging buffers (WRITE_SIZE 183 MB). With the
// cap released the ~200-230 VGPR allocation lands on the 8-waves/CU HW step,
// matching the 8 blocks/CU that LDS allows.
__global__ __launch_bounds__(TPB) void ori_loss_main(
    const float* __restrict__ scale,
    const int*   __restrict__ sidx,
    const int*   __restrict__ didx,
    const float* __restrict__ pred,
    const float* __restrict__ targ,
    int B, int ntiles, int nb,
    float* __restrict__ partial)
{
    extern __shared__ float lds[];
    float* lp = lds;               // [ROWS][PSTR]
    float* lt = lds + ROWS * PSTR; // [ROWS][TSTR]

    const int tid = threadIdx.x;
    const float s = scale[0];

    // wave-uniform gather indices -> SGPRs
    int sj[14], dj[14];
    #pragma unroll
    for (int k = 0; k < 14; ++k) { sj[k] = sidx[k] * 3; dj[k] = didx[k] * 3; }

    const float4* gp  = (const float4*)pred;  // B*18 granules
    const float4* gt4 = (const float4*)targ;  // B*78/4 granules
    const long maxp  = (long)B * 18 - 1;
    const long maxt4 = (long)B * 78 / 4 - 1;

    // DEPTH-2: two statically-named register buffers (no runtime indexing)
    float4 bpA[NP4], btA[NT4F + 1];
    float4 bpB[NP4], btB[NT4F + 1];

#define LOAD_PRED(buf, t)                                                      \
    { long basep = (long)(t) * (ROWS * 18);                                    \
      _Pragma("unroll")                                                        \
      for (int k = 0; k < NP4; ++k) {                                          \
          long i = basep + tid + TPB * k;                                      \
          buf[k] = gp[i > maxp ? maxp : i];                                    \
      } }
#define LOAD_TARG(buf, t)                                                      \
    { long baset = (long)(t) * TG4;                                            \
      _Pragma("unroll")                                                        \
      for (int k = 0; k < NT4F; ++k) {                                         \
          long i = baset + tid + TPB * k;                                      \
          buf[k] = gt4[i > maxt4 ? maxt4 : i];                                 \
      }                                                                        \
      { long i = baset + NT4F * TPB + tid;  /* rem granules; lanes>=48 dup */  \
        buf[NT4F] = gt4[i > maxt4 ? maxt4 : i]; } }

    // scatter one targ granule into padded LDS rows
    auto put_targ = [&](int gg, float4 v) {
        int f = gg * 4;
        int r = f / 78;
        int j = f - r * 78;       // even, 0..76
        float* d = lt + r * TSTR + j;
        if (j < 76) {
            d[0] = v.x; d[1] = v.y; d[2] = v.z; d[3] = v.w;
        } else {                  // straddles rows r / r+1
            d[0] = v.x; d[1] = v.y;
            float* d2 = lt + (r + 1) * TSTR;
            d2[0] = v.z; d2[1] = v.w;
        }
    };
    auto put_pred = [&](int gg, float4 v) {
        int r = gg / 18, j = gg - r * 18;
        float* d = lp + r * PSTR + j * 4;
        d[0] = v.x; d[1] = v.y; d[2] = v.z; d[3] = v.w;
    };

#define WRITE_TILE(bt, bp)                                                     \
    { _Pragma("unroll")                                                        \
      for (int k = 0; k < NT4F; ++k) put_targ(tid + TPB * k, bt[k]);           \
      if (tid < TG4 - NT4F * TPB) put_targ(tid + TPB * NT4F, bt[NT4F]);        \
      _Pragma("unroll")                                                        \
      for (int k = 0; k < NP4; ++k) put_pred(tid + TPB * k, bp[k]); }

    float sumj = 0.0f, sumc = 0.0f;

    auto compute = [&](int t) {
        int rows = min(ROWS, B - t * ROWS);
        if (tid < rows) {
            const float* pr = lp + tid * PSTR;
            const float* tr = lt + tid * TSTR;

            #pragma unroll
            for (int k = 0; k < 14; ++k) {
                #pragma unroll
                for (int c = 0; c < 3; ++c) {
                    float d  = s * pr[sj[k] + c] - tr[dj[k] + c];
                    float ad = fabsf(d);
                    sumj += (ad < 1.0f) ? 0.5f * d * d : (ad - 0.5f);
                }
            }

            #define P3(j) mk3(pr[(j)*3], pr[(j)*3+1], pr[(j)*3+2])
            #define T3(j) mk3(tr[(j)*3], tr[(j)*3+1], tr[(j)*3+2])
            sumc += cosv(cross3(sub3(P3(2), P3(0)), sub3(P3(1), P3(0))),
                         cross3(sub3(T3(22), T3(1)), sub3(T3(18), T3(1))));
            sumc += cosv(cross3(sub3(P3(13), P3(9)), sub3(P3(14), P3(9))),
                         cross3(sub3(T3(3), T3(2)), sub3(T3(11), T3(2))));
            #define DIR(pa, pb, ta, tb) sumc += cosv(sub3(P3(pa), P3(pb)), sub3(T3(ta), T3(tb)));
            DIR(2, 1, 22, 18)
            DIR(14, 13, 11, 4)
            DIR(6, 3, 2, 1)
            DIR(5, 2, 23, 22)
            DIR(4, 1, 19, 18)
            DIR(8, 5, 24, 23)
            DIR(7, 4, 20, 19)
            DIR(11, 8, 25, 24)
            DIR(10, 7, 21, 20)
            DIR(19, 17, 13, 12)
            DIR(18, 16, 6, 5)
            DIR(21, 19, 14, 13)
            DIR(20, 18, 7, 6)
            #undef DIR
            #undef P3
            #undef T3
        }
    };

    int t = blockIdx.x;
    // prologue: tiles t -> A, t+nb -> B, both in flight
    LOAD_TARG(btA, t)
    LOAD_PRED(bpA, t)
    {
        int t1 = t + nb;
        if (t1 < ntiles) { LOAD_TARG(btB, t1) LOAD_PRED(bpB, t1) }
    }

    for (;;) {
        int t1 = t + nb, t2 = t + 2 * nb;

        // ---- stage A (tile t), re-arm A with tile t+2nb ----
        WRITE_TILE(btA, bpA)
        if (t2 < ntiles) { LOAD_TARG(btA, t2) LOAD_PRED(bpA, t2) }
        asm volatile("" ::: "memory");
        compute(t);
        if (t1 >= ntiles) break;

        // ---- stage B (tile t+nb), re-arm B with tile t+3nb ----
        {
            int t3 = t + 3 * nb;
            WRITE_TILE(btB, bpB)
            if (t3 < ntiles) { LOAD_TARG(btB, t3) LOAD_PRED(bpB, t3) }
        }
        asm volatile("" ::: "memory");
        compute(t1);
        if (t2 >= ntiles) break;
        t = t2;
    }

    // ---- single-wave reduction (upper lanes hold 0) ----
    #pragma unroll
    for (int off = 32; off; off >>= 1) {
        sumj += __shfl_down(sumj, off);
        sumc += __shfl_down(sumc, off);
    }
    if (tid == 0) {
        partial[blockIdx.x]      = sumj;
        partial[nb + blockIdx.x] = sumc;
    }
#undef LOAD_PRED
#undef LOAD_TARG
#undef WRITE_TILE
}

__global__ __launch_bounds__(256) void ori_loss_final(
    const float* __restrict__ partial, int nblk, int B, float* __restrict__ out)
{
    double dj = 0.0, dc = 0.0;
    for (int i = threadIdx.x; i < nblk; i += 256) {
        dj += (double)partial[i];
        dc += (double)partial[nblk + i];
    }
    #pragma unroll
    for (int off = 32; off; off >>= 1) {
        dj += __shfl_down(dj, off);
        dc += __shfl_down(dc, off);
    }
    __shared__ double wj[4], wc[4];
    int wid  = threadIdx.x >> 6;
    int lane = threadIdx.x & 63;
    if (lane == 0) { wj[wid] = dj; wc[wid] = dc; }
    __syncthreads();
    if (threadIdx.x == 0) {
        double J = wj[0] + wj[1] + wj[2] + wj[3];
        double C = wc[0] + wc[1] + wc[2] + wc[3];
        double jtr  = J / ((double)B * 42.0);
        double loss = jtr + 15.0 - C / (double)B;
        out[0] = (float)loss;
        out[1] = (float)jtr;
    }
}

extern "C" void kernel_launch(void* const* d_in, const int* in_sizes, int n_in,
                              void* d_out, int out_size, void* d_ws, size_t ws_size,
                              hipStream_t stream) {
    const float* scale = (const float*)d_in[0];
    const int*   sidx  = (const int*)d_in[1];
    const int*   didx  = (const int*)d_in[2];
    const float* pred  = (const float*)d_in[3];
    const float* targ  = (const float*)d_in[4];

    int B      = in_sizes[3] / 72;               // pred_jtr is [B, 24, 3]
    int ntiles = (B + ROWS - 1) / ROWS;
    int nb     = ntiles < NBMAX ? ntiles : NBMAX;

    float* partial = (float*)d_ws;
    float* out     = (float*)d_out;

    ori_loss_main<<<nb, TPB, LDS_BYTES, stream>>>(scale, sidx, didx, pred, targ,
                                                  B, ntiles, nb, partial);
    ori_loss_final<<<1, 256, 0, stream>>>(partial, nb, B, out);
}

// Round 12
// 113.184 us; speedup vs baseline: 2.2073x; 1.2194x over previous
//
#include <hip/hip_runtime.h>

#define DEV __device__ __forceinline__

struct F3 { float x, y, z; };
DEV F3 mk3(float a, float b, float c) { F3 r; r.x = a; r.y = b; r.z = c; return r; }
DEV F3 sub3(F3 a, F3 b) { return mk3(a.x - b.x, a.y - b.y, a.z - b.z); }
DEV F3 cross3(F3 a, F3 b) {
    return mk3(a.y*b.z - a.z*b.y, a.z*b.x - a.x*b.z, a.x*b.y - a.y*b.x);
}
DEV float cosv(F3 a, F3 b) {
    float num = a.x*b.x + a.y*b.y + a.z*b.z;
    float na  = a.x*a.x + a.y*a.y + a.z*a.z;
    float nb  = b.x*b.x + b.y*b.y + b.z*b.z;
    return num * rsqrtf(na * nb);
}

constexpr int ROWS = 64;    // rows per tile
constexpr int TPB  = 64;    // ONE WAVE per block -> barrier-free wave-synchronous LDS
constexpr int PSTR = 73;    // padded pred row stride (odd -> conflict-free compute reads)
constexpr int TSTR = 79;    // padded targ row stride (odd)
constexpr int LDS_BYTES = ROWS * (PSTR + TSTR) * 4;  // 38,912 B -> 4 blocks/CU
constexpr int NBMAX = 1024; // 4 blocks/CU * 256 CUs

constexpr int TG4  = ROWS * 78 / 4;   // 1248 float4 granules of targ per tile (16B-aligned per tile)
constexpr int NT4  = 19;              // full per-lane float4 steps (+1 half-step for lanes<32)

__global__ __launch_bounds__(TPB, 1) void ori_loss_main(
    const float* __restrict__ scale,
    const int*   __restrict__ sidx,
    const int*   __restrict__ didx,
    const float* __restrict__ pred,
    const float* __restrict__ targ,
    int B, int ntiles, int nb,
    float* __restrict__ partial)
{
    extern __shared__ float lds[];
    float* lp = lds;               // [ROWS][PSTR]
    float* lt = lds + ROWS * PSTR; // [ROWS][TSTR]

    const int tid = threadIdx.x;
    const float s = scale[0];

    // wave-uniform gather indices -> SGPRs
    int sj[14], dj[14];
    #pragma unroll
    for (int k = 0; k < 14; ++k) { sj[k] = sidx[k] * 3; dj[k] = didx[k] * 3; }

    const float4* gp = (const float4*)pred;   // B*18 float4
    const float4* gt4 = (const float4*)targ;  // B*78/4 float4 granules (B even)
    const long maxp = (long)B * 18 - 1;
    const long maxt4 = (long)B * 78 / 4 - 1;

    float4 bp[18];
    float4 bt[NT4 + 1];   // +1 half-step granule (valid for lanes < 32)

    auto load_pred = [&](int t) {
        long basep = (long)t * (ROWS * 18);
        #pragma unroll
        for (int k = 0; k < 18; ++k) {
            long i = basep + tid + TPB * k;
            bp[k] = gp[i > maxp ? maxp : i];
        }
    };
    auto load_targ = [&](int t) {
        long baset = (long)t * TG4;
        #pragma unroll
        for (int k = 0; k < NT4; ++k) {
            long i = baset + tid + TPB * k;
            bt[k] = gt4[i > maxt4 ? maxt4 : i];
        }
        { // half-step: granules [1216, 1248); lanes >= 32 load clamped dup (unused)
            long i = baset + NT4 * TPB + tid;
            bt[NT4] = gt4[i > maxt4 ? maxt4 : i];
        }
    };

    // scatter one targ granule (4 consecutive floats at tile-float-offset 4*gg) into padded LDS
    auto put_targ = [&](int gg, float4 v) {
        int f = gg * 4;
        int r = f / 78;
        int j = f - r * 78;       // even, 0..76
        float* d = lt + r * TSTR + j;
        if (j < 76) {
            d[0] = v.x; d[1] = v.y; d[2] = v.z; d[3] = v.w;
        } else {                  // straddles rows r / r+1
            d[0] = v.x; d[1] = v.y;
            float* d2 = lt + (r + 1) * TSTR;
            d2[0] = v.z; d2[1] = v.w;
        }
    };

    float sumj = 0.0f, sumc = 0.0f;
    int t = blockIdx.x;
    load_targ(t);                          // prologue: tile t in flight
    load_pred(t);

    for (;;) {
        // NO barriers: single-wave block; LDS RAW ordered by lgkmcnt waits.
        int tn = t + nb;
        bool more = tn < ntiles;

        // ---- targ regs -> LDS, then immediately re-issue targ loads(t+1) ----
        #pragma unroll
        for (int k = 0; k < NT4; ++k) put_targ(tid + TPB * k, bt[k]);
        if (tid < 32)              put_targ(tid + TPB * NT4, bt[NT4]);
        if (more) load_targ(tn);           // in flight while pred writes run
        asm volatile("" ::: "memory");

        // ---- pred regs -> LDS, then re-issue pred loads(t+1) ----
        #pragma unroll
        for (int k = 0; k < 18; ++k) {
            int i = tid + TPB * k;
            int r = i / 18, j = i - r * 18;
            float* d = lp + r * PSTR + j * 4;
            d[0] = bp[k].x; d[1] = bp[k].y; d[2] = bp[k].z; d[3] = bp[k].w;
        }
        if (more) load_pred(tn);
        asm volatile("" ::: "memory");     // pin loads above compute (anti-sink)

        // ---- compute tile t from LDS ----
        int rows = min(ROWS, B - t * ROWS);
        if (tid < rows) {
            const float* pr = lp + tid * PSTR;
            const float* tr = lt + tid * TSTR;

            #pragma unroll
            for (int k = 0; k < 14; ++k) {
                #pragma unroll
                for (int c = 0; c < 3; ++c) {
                    float d  = s * pr[sj[k] + c] - tr[dj[k] + c];
                    float ad = fabsf(d);
                    sumj += (ad < 1.0f) ? 0.5f * d * d : (ad - 0.5f);
                }
            }

            #define P3(j) mk3(pr[(j)*3], pr[(j)*3+1], pr[(j)*3+2])
            #define T3(j) mk3(tr[(j)*3], tr[(j)*3+1], tr[(j)*3+2])
            sumc += cosv(cross3(sub3(P3(2), P3(0)), sub3(P3(1), P3(0))),
                         cross3(sub3(T3(22), T3(1)), sub3(T3(18), T3(1))));
            sumc += cosv(cross3(sub3(P3(13), P3(9)), sub3(P3(14), P3(9))),
                         cross3(sub3(T3(3), T3(2)), sub3(T3(11), T3(2))));
            #define DIR(pa, pb, ta, tb) sumc += cosv(sub3(P3(pa), P3(pb)), sub3(T3(ta), T3(tb)));
            DIR(2, 1, 22, 18)
            DIR(14, 13, 11, 4)
            DIR(6, 3, 2, 1)
            DIR(5, 2, 23, 22)
            DIR(4, 1, 19, 18)
            DIR(8, 5, 24, 23)
            DIR(7, 4, 20, 19)
            DIR(11, 8, 25, 24)
            DIR(10, 7, 21, 20)
            DIR(19, 17, 13, 12)
            DIR(18, 16, 6, 5)
            DIR(21, 19, 14, 13)
            DIR(20, 18, 7, 6)
            #undef DIR
            #undef P3
            #undef T3
        }

        if (!more) break;
        t = tn;
    }

    // ---- single-wave reduction ----
    #pragma unroll
    for (int off = 32; off; off >>= 1) {
        sumj += __shfl_down(sumj, off);
        sumc += __shfl_down(sumc, off);
    }
    if (tid == 0) {
        partial[blockIdx.x]      = sumj;
        partial[nb + blockIdx.x] = sumc;
    }
}

__global__ __launch_bounds__(256) void ori_loss_final(
    const float* __restrict__ partial, int nblk, int B, float* __restrict__ out)
{
    double dj = 0.0, dc = 0.0;
    for (int i = threadIdx.x; i < nblk; i += 256) {
        dj += (double)partial[i];
        dc += (double)partial[nblk + i];
    }
    #pragma unroll
    for (int off = 32; off; off >>= 1) {
        dj += __shfl_down(dj, off);
        dc += __shfl_down(dc, off);
    }
    __shared__ double wj[4], wc[4];
    int wid  = threadIdx.x >> 6;
    int lane = threadIdx.x & 63;
    if (lane == 0) { wj[wid] = dj; wc[wid] = dc; }
    __syncthreads();
    if (threadIdx.x == 0) {
        double J = wj[0] + wj[1] + wj[2] + wj[3];
        double C = wc[0] + wc[1] + wc[2] + wc[3];
        double jtr  = J / ((double)B * 42.0);
        double loss = jtr + 15.0 - C / (double)B;
        out[0] = (float)loss;
        out[1] = (float)jtr;
    }
}

extern "C" void kernel_launch(void* const* d_in, const int* in_sizes, int n_in,
                              void* d_out, int out_size, void* d_ws, size_t ws_size,
                              hipStream_t stream) {
    const float* scale = (const float*)d_in[0];
    const int*   sidx  = (const int*)d_in[1];
    const int*   didx  = (const int*)d_in[2];
    const float* pred  = (const float*)d_in[3];
    const float* targ  = (const float*)d_in[4];

    int B      = in_sizes[3] / 72;               // pred_jtr is [B, 24, 3]
    int ntiles = (B + ROWS - 1) / ROWS;
    int nb     = ntiles < NBMAX ? ntiles : NBMAX;

    float* partial = (float*)d_ws;
    float* out     = (float*)d_out;

    ori_loss_main<<<nb, TPB, LDS_BYTES, stream>>>(scale, sidx, didx, pred, targ,
                                                  B, ntiles, nb, partial);
    ori_loss_final<<<1, 256, 0, stream>>>(partial, nb, B, out);
}